// Round 17
// baseline (471.590 us; speedup 1.0000x reference)
//
#include <hip/hip_runtime.h>
#include <hip/hip_bf16.h>

#define S_TOT 5440
#define C_DIM 256
#define F_DIM 1024
#define N_LAYERS 6

__device__ __constant__ int c_HW[4]    = {64, 32, 16, 8};
__device__ __constant__ int c_logW[4]  = {6, 5, 4, 3};
__device__ __constant__ int c_start[4] = {0, 4096, 5120, 5376};

typedef __attribute__((ext_vector_type(8))) short bf16x8;
typedef __attribute__((ext_vector_type(4))) float f32x4;
typedef __attribute__((ext_vector_type(4))) unsigned int u32x4;

__device__ __forceinline__ short f2bf(float f) {
    __hip_bfloat16 h = __float2bfloat16(f);
    return *reinterpret_cast<short*>(&h);
}
union uf32 { unsigned int u; float f; };
__device__ __forceinline__ float lo_f(unsigned int u) { uf32 c; c.u = u << 16;          return c.f; }
__device__ __forceinline__ float hi_f(unsigned int u) { uf32 c; c.u = u & 0xffff0000u; return c.f; }
__device__ __forceinline__ float bf2f(unsigned short u) { uf32 c; c.u = ((unsigned int)u) << 16; return c.f; }

// ---------------- weight prep: fp32 [K][N] -> bf16 [N][K], all 36 matrices ----------------
__global__ __launch_bounds__(256) void prep_weights(
    const float* __restrict__ Wv, const float* __restrict__ Woff,
    const float* __restrict__ Wattn, const float* __restrict__ Wout,
    const float* __restrict__ W1, const float* __restrict__ W2,
    unsigned short* __restrict__ WT)
{
    __shared__ short T[64][72];
    const int bid = blockIdx.x;
    const int layer = bid / 184;
    const int r = bid % 184;
    const float* src; unsigned short* dst; int K, N, kb, nb;
    if (r < 16)       { src = Wv    + (long)layer*65536;  dst = WT + 0       + (long)layer*65536;  K=256;  N=256;  kb=r&3;        nb=r>>2; }
    else if (r < 32)  { src = Woff  + (long)layer*65536;  dst = WT + 393216  + (long)layer*65536;  K=256;  N=256;  kb=(r-16)&3;   nb=(r-16)>>2; }
    else if (r < 40)  { src = Wattn + (long)layer*32768;  dst = WT + 786432  + (long)layer*32768;  K=256;  N=128;  kb=(r-32)&3;   nb=(r-32)>>2; }
    else if (r < 56)  { src = Wout  + (long)layer*65536;  dst = WT + 983040  + (long)layer*65536;  K=256;  N=256;  kb=(r-40)&3;   nb=(r-40)>>2; }
    else if (r < 120) { src = W1    + (long)layer*262144; dst = WT + 1376256 + (long)layer*262144; K=256;  N=1024; kb=(r-56)&3;   nb=(r-56)>>2; }
    else              { src = W2    + (long)layer*262144; dst = WT + 2949120 + (long)layer*262144; K=1024; N=256;  kb=(r-120)&15; nb=(r-120)>>4; }
    const int k0 = kb * 64, n0 = nb * 64;
    const int t = threadIdx.x;
    {
        const int row = t >> 2, cg = (t & 3) * 16;
        const float* sp = src + (long)(k0 + row) * N + n0 + cg;
        float4 v0 = *(const float4*)sp;
        float4 v1 = *(const float4*)(sp + 4);
        float4 v2 = *(const float4*)(sp + 8);
        float4 v3 = *(const float4*)(sp + 12);
        short tmp[16];
        tmp[0]=f2bf(v0.x); tmp[1]=f2bf(v0.y); tmp[2]=f2bf(v0.z); tmp[3]=f2bf(v0.w);
        tmp[4]=f2bf(v1.x); tmp[5]=f2bf(v1.y); tmp[6]=f2bf(v1.z); tmp[7]=f2bf(v1.w);
        tmp[8]=f2bf(v2.x); tmp[9]=f2bf(v2.y); tmp[10]=f2bf(v2.z); tmp[11]=f2bf(v2.w);
        tmp[12]=f2bf(v3.x); tmp[13]=f2bf(v3.y); tmp[14]=f2bf(v3.z); tmp[15]=f2bf(v3.w);
        *(bf16x8*)&T[row][cg]     = *(bf16x8*)&tmp[0];
        *(bf16x8*)&T[row][cg + 8] = *(bf16x8*)&tmp[8];
    }
    __syncthreads();
    {
        const int n = t >> 2, kg = (t & 3) * 16;
        short o[16];
        #pragma unroll
        for (int j = 0; j < 16; ++j) o[j] = T[kg + j][n];
        unsigned short* dp = dst + (long)(n0 + n) * K + k0 + kg;
        *(bf16x8*)dp       = *(bf16x8*)&o[0];
        *(bf16x8*)(dp + 8) = *(bf16x8*)&o[8];
    }
}

// ============ A-prep (32 rows): fp32 32x256 tile, optional LN/+pos/xout, -> bf16 LDS ============
__device__ __forceinline__ void prep_A32(
    const float* __restrict__ Ain, const float* __restrict__ g,
    const float* __restrict__ b, const float* __restrict__ pos,
    float* __restrict__ xout, int mBase, int doLN,
    short (*As)[264])
{
    const int t = threadIdx.x;
    const int row = t >> 3, q8 = t & 7;      // 32 rows, 8 col-groups of 32
    const long gbase = (long)(mBase + row) * 256 + q8 * 32;
    float va[32];
    #pragma unroll
    for (int j = 0; j < 8; ++j) {
        float4 v = *(const float4*)(Ain + gbase + j * 4);
        va[j*4+0] = v.x; va[j*4+1] = v.y; va[j*4+2] = v.z; va[j*4+3] = v.w;
    }
    if (doLN) {
        float s1 = 0.f, s2 = 0.f;
        #pragma unroll
        for (int j = 0; j < 32; ++j) { s1 += va[j]; s2 += va[j] * va[j]; }
        s1 += __shfl_xor(s1, 1); s2 += __shfl_xor(s2, 1);
        s1 += __shfl_xor(s1, 2); s2 += __shfl_xor(s2, 2);
        s1 += __shfl_xor(s1, 4); s2 += __shfl_xor(s2, 4);
        const float mean = s1 * (1.f / 256.f);
        const float var  = s2 * (1.f / 256.f) - mean * mean;
        const float rstd = rsqrtf(var + 1e-5f);
        #pragma unroll
        for (int j = 0; j < 8; ++j) {
            float4 g4 = *(const float4*)(g + q8 * 32 + j * 4);
            float4 b4 = *(const float4*)(b + q8 * 32 + j * 4);
            va[j*4+0] = (va[j*4+0] - mean) * rstd * g4.x + b4.x;
            va[j*4+1] = (va[j*4+1] - mean) * rstd * g4.y + b4.y;
            va[j*4+2] = (va[j*4+2] - mean) * rstd * g4.z + b4.z;
            va[j*4+3] = (va[j*4+3] - mean) * rstd * g4.w + b4.w;
        }
    }
    if (xout) {
        #pragma unroll
        for (int j = 0; j < 8; ++j) {
            float4 v;
            v.x = va[j*4+0]; v.y = va[j*4+1]; v.z = va[j*4+2]; v.w = va[j*4+3];
            *(float4*)(xout + gbase + j * 4) = v;
        }
    }
    if (pos) {
        #pragma unroll
        for (int j = 0; j < 8; ++j) {
            float4 p = *(const float4*)(pos + gbase + j * 4);
            va[j*4+0] += p.x; va[j*4+1] += p.y; va[j*4+2] += p.z; va[j*4+3] += p.w;
        }
    }
    #pragma unroll
    for (int j8 = 0; j8 < 4; ++j8) {
        short tmp[8];
        #pragma unroll
        for (int e = 0; e < 8; ++e) tmp[e] = f2bf(va[j8 * 8 + e]);
        *(bf16x8*)&As[row][q8 * 32 + j8 * 8] = *(bf16x8*)tmp;
    }
}

// ============ 32-row GEMM core, A resident in LDS (K=256), B streamed BK=64 ============
// Register-prefetch rotation: next chunk's loads issue before current MFMA block.
template<int NF>
__device__ __forceinline__ void core32_Alds(
    const unsigned short* __restrict__ Bt, int nBase,
    const short (*As)[264], short (*Bs)[72], f32x4 (&acc)[NF])
{
    const int t = threadIdx.x;
    const int lane = t & 63, wave = t >> 6;
    const int wr = wave >> 1, wc = wave & 1;
    const int lr = lane & 15;

    #pragma unroll
    for (int j = 0; j < NF; ++j) acc[j] = (f32x4){0.f, 0.f, 0.f, 0.f};

    bf16x8 rb[NF];
    #pragma unroll
    for (int q = 0; q < NF; ++q) {
        int flat = q * 256 + t, row = flat >> 3, cg = (flat & 7) * 8;
        rb[q] = *(const bf16x8*)(Bt + (long)(nBase + row) * 256 + cg);
    }

    #pragma unroll
    for (int k0 = 0; k0 < 256; k0 += 64) {
        __syncthreads();
        #pragma unroll
        for (int q = 0; q < NF; ++q) {
            int flat = q * 256 + t, row = flat >> 3, cg = (flat & 7) * 8;
            *(bf16x8*)&Bs[row][cg] = rb[q];
        }
        __syncthreads();
        if (k0 < 192) {
            #pragma unroll
            for (int q = 0; q < NF; ++q) {
                int flat = q * 256 + t, row = flat >> 3, cg = (flat & 7) * 8;
                rb[q] = *(const bf16x8*)(Bt + (long)(nBase + row) * 256 + k0 + 64 + cg);
            }
        }
        #pragma unroll
        for (int kk = 0; kk < 2; ++kk) {
            const int lks = kk * 32 + (lane >> 4) * 8;
            bf16x8 af = *(const bf16x8*)&As[wr * 16 + lr][k0 + lks];
            #pragma unroll
            for (int fn = 0; fn < NF; ++fn) {
                bf16x8 bfr = *(bf16x8*)&Bs[wc * (NF * 16) + fn * 16 + lr][lks];
                acc[fn] = __builtin_amdgcn_mfma_f32_16x16x32_bf16(af, bfr, acc[fn], 0, 0, 0);
            }
        }
    }
}

// ============ 32-row GEMM core, A bf16 from global, B streamed, BK=64, prefetch-rotated ============
template<int NF>
__device__ __forceinline__ void core32_g(
    const unsigned short* __restrict__ A, const unsigned short* __restrict__ Bt,
    int K, int mBase, int nBase, short (*As)[72], short (*Bs)[72],
    f32x4 (&acc)[NF])
{
    const int t = threadIdx.x;
    const int lane = t & 63, wave = t >> 6;
    const int wr = wave >> 1, wc = wave & 1;
    const int lr = lane & 15;
    const int arow = t >> 3, acg = (t & 7) * 8;

    #pragma unroll
    for (int j = 0; j < NF; ++j) acc[j] = (f32x4){0.f, 0.f, 0.f, 0.f};

    bf16x8 ra, rb[NF];
    ra = *(const bf16x8*)(A + (long)(mBase + arow) * K + acg);
    #pragma unroll
    for (int q = 0; q < NF; ++q) {
        int flat = q * 256 + t, row = flat >> 3, cg = (flat & 7) * 8;
        rb[q] = *(const bf16x8*)(Bt + (long)(nBase + row) * K + cg);
    }

    for (int k0 = 0; k0 < K; k0 += 64) {
        __syncthreads();
        *(bf16x8*)&As[arow][acg] = ra;
        #pragma unroll
        for (int q = 0; q < NF; ++q) {
            int flat = q * 256 + t, row = flat >> 3, cg = (flat & 7) * 8;
            *(bf16x8*)&Bs[row][cg] = rb[q];
        }
        __syncthreads();
        if (k0 + 64 < K) {
            ra = *(const bf16x8*)(A + (long)(mBase + arow) * K + k0 + 64 + acg);
            #pragma unroll
            for (int q = 0; q < NF; ++q) {
                int flat = q * 256 + t, row = flat >> 3, cg = (flat & 7) * 8;
                rb[q] = *(const bf16x8*)(Bt + (long)(nBase + row) * K + k0 + 64 + cg);
            }
        }
        #pragma unroll
        for (int kk = 0; kk < 2; ++kk) {
            const int lks = kk * 32 + (lane >> 4) * 8;
            bf16x8 af = *(bf16x8*)&As[wr * 16 + lr][lks];
            #pragma unroll
            for (int fn = 0; fn < NF; ++fn) {
                bf16x8 bfr = *(bf16x8*)&Bs[wc * (NF * 16) + fn * 16 + lr][lks];
                acc[fn] = __builtin_amdgcn_mfma_f32_16x16x32_bf16(af, bfr, acc[fn], 0, 0, 0);
            }
        }
    }
}

// ---------------- fused LN2 + projections (grid 170 x 5); 32-row tiles, BK=64 ----------------
__global__ __launch_bounds__(256) void proj_ln(
    const float* __restrict__ Ain, const float* __restrict__ pos,
    const float* __restrict__ g, const float* __restrict__ b,
    const unsigned short* __restrict__ WvT, const float* __restrict__ bv,
    const unsigned short* __restrict__ WofT, const float* __restrict__ bof,
    const unsigned short* __restrict__ WatT, const float* __restrict__ bat,
    unsigned short* __restrict__ value_bf, unsigned short* __restrict__ offraw,
    unsigned short* __restrict__ logits, float* __restrict__ xcur, int doLN)
{
    __shared__ short As[32][264];
    __shared__ short Bs[128][72];
    const int ny = blockIdx.y, mBase = blockIdx.x * 32;
    const unsigned short* Bp; const float* bias; int nBase, kind;
    if (ny < 2)      { Bp = WvT;  bias = bv;  nBase = ny * 128;       kind = 0; }
    else if (ny < 4) { Bp = WofT; bias = bof; nBase = (ny - 2) * 128; kind = 1; }
    else             { Bp = WatT; bias = bat; nBase = 0;              kind = 2; }

    prep_A32(Ain, g, b, (kind > 0) ? pos : nullptr,
             (doLN && ny == 0) ? xcur : nullptr, mBase, doLN, As);

    f32x4 acc[4];
    core32_Alds<4>(Bp, nBase, As, Bs, acc);

    const int lane = threadIdx.x & 63, wave = threadIdx.x >> 6;
    const int wr = wave >> 1, wc = wave & 1;
    #pragma unroll
    for (int fn = 0; fn < 4; ++fn)
        #pragma unroll
        for (int r = 0; r < 4; ++r) {
            int m = mBase + wr * 16 + (lane >> 4) * 4 + r;
            int n = nBase + wc * 64 + fn * 16 + (lane & 15);
            float v = acc[fn][r] + bias[n];
            if (kind == 0)      value_bf[(long)m * 256 + n] = (unsigned short)f2bf(v);
            else if (kind == 1) offraw[(long)m * 256 + n] = (unsigned short)f2bf(v);
            else                logits[(long)m * 128 + n] = (unsigned short)f2bf(v);
        }
}

// ---------------- fused LN1 + W1 GEMM + relu (grid 170 x 8, NF=4, 32x128 tile) ----------------
__global__ __launch_bounds__(256) void gemm_w1ln(
    const float* __restrict__ Ain, const float* __restrict__ g,
    const float* __restrict__ b, const unsigned short* __restrict__ W1T,
    const float* __restrict__ bias, unsigned short* __restrict__ hbuf,
    float* __restrict__ xout)
{
    __shared__ short As[32][264];
    __shared__ short Bs[128][72];
    const int mBase = blockIdx.x * 32, nBase = blockIdx.y * 128;

    prep_A32(Ain, g, b, nullptr, (blockIdx.y == 0) ? xout : nullptr, mBase, 1, As);

    f32x4 acc[4];
    core32_Alds<4>(W1T, nBase, As, Bs, acc);

    const int lane = threadIdx.x & 63, wave = threadIdx.x >> 6;
    const int wr = wave >> 1, wc = wave & 1;
    #pragma unroll
    for (int fn = 0; fn < 4; ++fn)
        #pragma unroll
        for (int r = 0; r < 4; ++r) {
            int m = mBase + wr * 16 + (lane >> 4) * 4 + r;
            int n = nBase + wc * 64 + fn * 16 + (lane & 15);
            float v = fmaxf(acc[fn][r] + bias[n], 0.f);
            hbuf[(long)m * 1024 + n] = (unsigned short)f2bf(v);
        }
}

// ---------------- plain GEMM (N=256) + bias + residual -> fp32 (grid 170 x 4, 32x64 tile) ----------------
__global__ __launch_bounds__(256) void gemm_res(
    const unsigned short* __restrict__ A, const unsigned short* __restrict__ Bt,
    const float* __restrict__ bias, const float* __restrict__ res,
    float* __restrict__ out, int K)
{
    __shared__ short As[32][72];
    __shared__ short Bs[64][72];
    const int mBase = blockIdx.x * 32, nBase = blockIdx.y * 64;
    f32x4 acc[2];
    core32_g<2>(A, Bt, K, mBase, nBase, As, Bs, acc);

    const int lane = threadIdx.x & 63, wave = threadIdx.x >> 6;
    const int wr = wave >> 1, wc = wave & 1;
    #pragma unroll
    for (int fn = 0; fn < 2; ++fn)
        #pragma unroll
        for (int r = 0; r < 4; ++r) {
            int m = mBase + wr * 16 + (lane >> 4) * 4 + r;
            int n = nBase + wc * 32 + fn * 16 + (lane & 15);
            out[(long)m * 256 + n] = acc[fn][r] + bias[n] + res[(long)m * 256 + n];
        }
}

// ---------------- MSDA sampling v6: all 16 gathers hoisted before FMA ----------------
__global__ __launch_bounds__(256) void msda2(
    const unsigned short* __restrict__ value, const unsigned short* __restrict__ offraw,
    const unsigned short* __restrict__ logits, const float* __restrict__ vr,
    unsigned short* __restrict__ outB)
{
    const int t = threadIdx.x;
    const int q = t >> 7, tt = t & 127;
    const int s = blockIdx.x * 2 + q;

    __shared__ int4   sIdx[2][128];
    __shared__ float4 sW[2][128];

    {
        const int pt = tt & 15, l = pt >> 2;

        float lg = bf2f(logits[(long)s * 128 + tt]);
        float m = lg;
        #pragma unroll
        for (int o = 1; o < 16; o <<= 1) m = fmaxf(m, __shfl_xor(m, o));
        float e = expf(lg - m);
        float sum = e;
        #pragma unroll
        for (int o = 1; o < 16; o <<= 1) sum += __shfl_xor(sum, o);
        float aw = e / sum;

        int ls = (s < 4096) ? 0 : (s < 5120) ? 1 : (s < 5376) ? 2 : 3;
        int lw = c_logW[ls];
        int Wq = c_HW[ls];
        int rem = s - c_start[ls];
        int qi = rem >> lw, qj = rem & (Wq - 1);
        float xh = (qj + 0.5f) / (vr[ls * 2 + 1] * (float)Wq);
        float yh = (qi + 0.5f) / (vr[ls * 2 + 0] * (float)Wq);

        const int Wl = c_HW[l], sl = c_start[l];
        const float fW = (float)Wl;
        float refx = xh * vr[l * 2 + 1];
        float refy = yh * vr[l * 2 + 0];
        unsigned int uoxy = *(const unsigned int*)(offraw + (long)s * 256 + tt * 2);
        float ox = lo_f(uoxy), oy = hi_f(uoxy);
        float x = refx * fW + ox - 0.5f;
        float y = refy * fW + oy - 0.5f;
        float x0f = floorf(x), y0f = floorf(y);
        float fx = x - x0f, fy = y - y0f;
        int x0 = (int)x0f, y0 = (int)y0f;
        int x1 = x0 + 1, y1 = y0 + 1;
        float vx0 = (x0 >= 0 && x0 < Wl) ? 1.f : 0.f;
        float vx1 = (x1 >= 0 && x1 < Wl) ? 1.f : 0.f;
        float vy0 = (y0 >= 0 && y0 < Wl) ? 1.f : 0.f;
        float vy1 = (y1 >= 0 && y1 < Wl) ? 1.f : 0.f;
        int cx0 = min(max(x0, 0), Wl - 1), cx1 = min(max(x1, 0), Wl - 1);
        int cy0 = min(max(y0, 0), Wl - 1), cy1 = min(max(y1, 0), Wl - 1);

        int4 id4;
        id4.x = sl + cy0 * Wl + cx0;
        id4.y = sl + cy0 * Wl + cx1;
        id4.z = sl + cy1 * Wl + cx0;
        id4.w = sl + cy1 * Wl + cx1;
        sIdx[q][tt] = id4;
        float4 w4;
        w4.x = aw * (1.f - fx) * (1.f - fy) * vx0 * vy0;
        w4.y = aw * fx * (1.f - fy) * vx1 * vy0;
        w4.z = aw * (1.f - fx) * fy * vx0 * vy1;
        w4.w = aw * fx * fy * vx1 * vy1;
        sW[q][tt] = w4;
    }
    __syncthreads();

    // phase 2: h = tt>>4, pg = (tt>>2)&3, dq = tt&3 (dq fastest -> coalesced)
    const int h = tt >> 4, pg = (tt >> 2) & 3, dq = tt & 3;
    const int cb = h * 32 + dq * 8;

    int4   ids[4];
    float4 w4s[4];
    #pragma unroll
    for (int p = 0; p < 4; ++p) {
        const int ei = h * 16 + pg * 4 + p;
        ids[p] = sIdx[q][ei];
        w4s[p] = sW[q][ei];
    }
    u32x4 u[16];
    #pragma unroll
    for (int p = 0; p < 4; ++p) {
        u[p*4+0] = *(const u32x4*)(value + (long)ids[p].x * 256 + cb);
        u[p*4+1] = *(const u32x4*)(value + (long)ids[p].y * 256 + cb);
        u[p*4+2] = *(const u32x4*)(value + (long)ids[p].z * 256 + cb);
        u[p*4+3] = *(const u32x4*)(value + (long)ids[p].w * 256 + cb);
    }

    float a8[8] = {0.f,0.f,0.f,0.f,0.f,0.f,0.f,0.f};
    #pragma unroll
    for (int p = 0; p < 4; ++p) {
        float4 w = w4s[p];
        #pragma unroll
        for (int j = 0; j < 4; ++j) {
            a8[2*j]   += w.x * lo_f(u[p*4+0][j]) + w.y * lo_f(u[p*4+1][j])
                       + w.z * lo_f(u[p*4+2][j]) + w.w * lo_f(u[p*4+3][j]);
            a8[2*j+1] += w.x * hi_f(u[p*4+0][j]) + w.y * hi_f(u[p*4+1][j])
                       + w.z * hi_f(u[p*4+2][j]) + w.w * hi_f(u[p*4+3][j]);
        }
    }
    #pragma unroll
    for (int j = 0; j < 8; ++j) {
        a8[j] += __shfl_xor(a8[j], 4);
        a8[j] += __shfl_xor(a8[j], 8);
    }
    if (pg == 0) {
        short o8[8];
        #pragma unroll
        for (int j = 0; j < 8; ++j) o8[j] = f2bf(a8[j]);
        *(bf16x8*)(outB + (long)s * 256 + cb) = *(bf16x8*)o8;
    }
}

// ---------------- final LayerNorm: one wave per row ----------------
__global__ __launch_bounds__(256) void ln4f(
    const float* __restrict__ in, const float* __restrict__ g,
    const float* __restrict__ b, float* __restrict__ out)
{
    const int wave = threadIdx.x >> 6, lane = threadIdx.x & 63;
    const int s = blockIdx.x * 4 + wave;
    f32x4 v = *(const f32x4*)(in + (long)s * 256 + lane * 4);

    float sum = v[0] + v[1] + v[2] + v[3];
    #pragma unroll
    for (int o = 1; o < 64; o <<= 1) sum += __shfl_xor(sum, o);
    const float mean = sum * (1.f / 256.f);

    f32x4 d = v - mean;
    float sq = d[0]*d[0] + d[1]*d[1] + d[2]*d[2] + d[3]*d[3];
    #pragma unroll
    for (int o = 1; o < 64; o <<= 1) sq += __shfl_xor(sq, o);
    const float rstd = rsqrtf(sq * (1.f / 256.f) + 1e-5f);

    f32x4 gg = *(const f32x4*)(g + lane * 4);
    f32x4 bb = *(const f32x4*)(b + lane * 4);
    f32x4 o4 = d * rstd * gg + bb;
    *(f32x4*)(out + (long)s * 256 + lane * 4) = o4;
}

extern "C" void kernel_launch(void* const* d_in, const int* in_sizes, int n_in,
                              void* d_out, int out_size, void* d_ws, size_t ws_size,
                              hipStream_t stream) {
    const float* src   = (const float*)d_in[0];
    const float* pos   = (const float*)d_in[1];
    const float* vr    = (const float*)d_in[2];
    const float* Wv    = (const float*)d_in[5];
    const float* bv    = (const float*)d_in[6];
    const float* Woff  = (const float*)d_in[7];
    const float* boff  = (const float*)d_in[8];
    const float* Wattn = (const float*)d_in[9];
    const float* battn = (const float*)d_in[10];
    const float* Wout  = (const float*)d_in[11];
    const float* bout  = (const float*)d_in[12];
    const float* ln1g  = (const float*)d_in[13];
    const float* ln1b  = (const float*)d_in[14];
    const float* W1    = (const float*)d_in[15];
    const float* b1    = (const float*)d_in[16];
    const float* W2    = (const float*)d_in[17];
    const float* b2    = (const float*)d_in[18];
    const float* ln2g  = (const float*)d_in[19];
    const float* ln2b  = (const float*)d_in[20];

    const int S = S_TOT, C = C_DIM;
    const long SC = (long)S * C;

    // fp32 region
    float* ws     = (float*)d_ws;
    float* tmp2   = ws;                        // SC f32 (layer output, pre-LN2)
    float* xcur   = tmp2 + SC;                 // SC f32 (LN2 out = layer input x)
    float* xln1   = xcur + SC;                 // SC f32 (LN1 out, residual for W2)
    // bf16 region
    unsigned short* offraw_bf = (unsigned short*)(xln1 + SC);      // SC
    unsigned short* logits_bf = offraw_bf + SC;                    // S*128
    unsigned short* value_bf  = logits_bf + (long)S * 128;         // SC
    unsigned short* msda_bf   = value_bf + SC;                     // SC
    unsigned short* hbuf_bf   = msda_bf + SC;                      // S*F
    unsigned short* WT        = hbuf_bf + (long)S * F_DIM;         // 4521984

    const unsigned short* WvT  = WT + 0;
    const unsigned short* WofT = WT + 393216;
    const unsigned short* WatT = WT + 786432;
    const unsigned short* WouT = WT + 983040;
    const unsigned short* W1T  = WT + 1376256;
    const unsigned short* W2T  = WT + 2949120;

    prep_weights<<<1104, 256, 0, stream>>>(Wv, Woff, Wattn, Wout, W1, W2, WT);

    for (int i = 0; i < N_LAYERS; ++i) {
        const float* Ain = (i == 0) ? src : tmp2;
        const float* g2  = (i == 0) ? nullptr : ln2g + (long)(i - 1) * C;
        const float* bb2 = (i == 0) ? nullptr : ln2b + (long)(i - 1) * C;
        const float* resWout = (i == 0) ? src : xcur;

        proj_ln<<<dim3(170, 5), 256, 0, stream>>>(
            Ain, pos, g2, bb2,
            WvT + (long)i * 65536, bv + (long)i * C,
            WofT + (long)i * 65536, boff + (long)i * 256,
            WatT + (long)i * 32768, battn + (long)i * 128,
            value_bf, offraw_bf, logits_bf, xcur, (i == 0) ? 0 : 1);

        msda2<<<S / 2, 256, 0, stream>>>(value_bf, offraw_bf, logits_bf, vr, msda_bf);

        gemm_res<<<dim3(170, 4), 256, 0, stream>>>(
            msda_bf, WouT + (long)i * 65536, bout + (long)i * C, resWout, tmp2, 256);

        gemm_w1ln<<<dim3(170, 8), 256, 0, stream>>>(
            tmp2, ln1g + (long)i * C, ln1b + (long)i * C,
            W1T + (long)i * 262144, b1 + (long)i * F_DIM, hbuf_bf, xln1);

        gemm_res<<<dim3(170, 4), 256, 0, stream>>>(
            hbuf_bf, W2T + (long)i * 262144, b2 + (long)i * C, xln1, tmp2, 1024);
    }

    ln4f<<<S / 4, 256, 0, stream>>>(
        tmp2, ln2g + (long)(N_LAYERS - 1) * C, ln2b + (long)(N_LAYERS - 1) * C,
        (float*)d_out);
}

// Round 18
// 418.717 us; speedup vs baseline: 1.1263x; 1.1263x over previous
//
#include <hip/hip_runtime.h>
#include <hip/hip_bf16.h>

#define S_TOT 5440
#define C_DIM 256
#define F_DIM 1024
#define N_LAYERS 6

__device__ __constant__ int c_HW[4]    = {64, 32, 16, 8};
__device__ __constant__ int c_logW[4]  = {6, 5, 4, 3};
__device__ __constant__ int c_start[4] = {0, 4096, 5120, 5376};

typedef __attribute__((ext_vector_type(8))) short bf16x8;
typedef __attribute__((ext_vector_type(4))) float f32x4;
typedef __attribute__((ext_vector_type(4))) unsigned int u32x4;

__device__ __forceinline__ short f2bf(float f) {
    __hip_bfloat16 h = __float2bfloat16(f);
    return *reinterpret_cast<short*>(&h);
}
union uf32 { unsigned int u; float f; };
__device__ __forceinline__ float lo_f(unsigned int u) { uf32 c; c.u = u << 16;          return c.f; }
__device__ __forceinline__ float hi_f(unsigned int u) { uf32 c; c.u = u & 0xffff0000u; return c.f; }
__device__ __forceinline__ float bf2f(unsigned short u) { uf32 c; c.u = ((unsigned int)u) << 16; return c.f; }

// ---------------- weight prep: fp32 [K][N] -> bf16 [N][K], all 36 matrices ----------------
__global__ __launch_bounds__(256) void prep_weights(
    const float* __restrict__ Wv, const float* __restrict__ Woff,
    const float* __restrict__ Wattn, const float* __restrict__ Wout,
    const float* __restrict__ W1, const float* __restrict__ W2,
    unsigned short* __restrict__ WT)
{
    __shared__ short T[64][72];
    const int bid = blockIdx.x;
    const int layer = bid / 184;
    const int r = bid % 184;
    const float* src; unsigned short* dst; int K, N, kb, nb;
    if (r < 16)       { src = Wv    + (long)layer*65536;  dst = WT + 0       + (long)layer*65536;  K=256;  N=256;  kb=r&3;        nb=r>>2; }
    else if (r < 32)  { src = Woff  + (long)layer*65536;  dst = WT + 393216  + (long)layer*65536;  K=256;  N=256;  kb=(r-16)&3;   nb=(r-16)>>2; }
    else if (r < 40)  { src = Wattn + (long)layer*32768;  dst = WT + 786432  + (long)layer*32768;  K=256;  N=128;  kb=(r-32)&3;   nb=(r-32)>>2; }
    else if (r < 56)  { src = Wout  + (long)layer*65536;  dst = WT + 983040  + (long)layer*65536;  K=256;  N=256;  kb=(r-40)&3;   nb=(r-40)>>2; }
    else if (r < 120) { src = W1    + (long)layer*262144; dst = WT + 1376256 + (long)layer*262144; K=256;  N=1024; kb=(r-56)&3;   nb=(r-56)>>2; }
    else              { src = W2    + (long)layer*262144; dst = WT + 2949120 + (long)layer*262144; K=1024; N=256;  kb=(r-120)&15; nb=(r-120)>>4; }
    const int k0 = kb * 64, n0 = nb * 64;
    const int t = threadIdx.x;
    {
        const int row = t >> 2, cg = (t & 3) * 16;
        const float* sp = src + (long)(k0 + row) * N + n0 + cg;
        float4 v0 = *(const float4*)sp;
        float4 v1 = *(const float4*)(sp + 4);
        float4 v2 = *(const float4*)(sp + 8);
        float4 v3 = *(const float4*)(sp + 12);
        short tmp[16];
        tmp[0]=f2bf(v0.x); tmp[1]=f2bf(v0.y); tmp[2]=f2bf(v0.z); tmp[3]=f2bf(v0.w);
        tmp[4]=f2bf(v1.x); tmp[5]=f2bf(v1.y); tmp[6]=f2bf(v1.z); tmp[7]=f2bf(v1.w);
        tmp[8]=f2bf(v2.x); tmp[9]=f2bf(v2.y); tmp[10]=f2bf(v2.z); tmp[11]=f2bf(v2.w);
        tmp[12]=f2bf(v3.x); tmp[13]=f2bf(v3.y); tmp[14]=f2bf(v3.z); tmp[15]=f2bf(v3.w);
        *(bf16x8*)&T[row][cg]     = *(bf16x8*)&tmp[0];
        *(bf16x8*)&T[row][cg + 8] = *(bf16x8*)&tmp[8];
    }
    __syncthreads();
    {
        const int n = t >> 2, kg = (t & 3) * 16;
        short o[16];
        #pragma unroll
        for (int j = 0; j < 16; ++j) o[j] = T[kg + j][n];
        unsigned short* dp = dst + (long)(n0 + n) * K + k0 + kg;
        *(bf16x8*)dp       = *(bf16x8*)&o[0];
        *(bf16x8*)(dp + 8) = *(bf16x8*)&o[8];
    }
}

// ============ A-prep (32 rows): fp32 32x256 tile, optional LN/+pos/xout, -> bf16 LDS ============
__device__ __forceinline__ void prep_A32(
    const float* __restrict__ Ain, const float* __restrict__ g,
    const float* __restrict__ b, const float* __restrict__ pos,
    float* __restrict__ xout, int mBase, int doLN,
    short (*As)[264])
{
    const int t = threadIdx.x;
    const int row = t >> 3, q8 = t & 7;      // 32 rows, 8 col-groups of 32
    const long gbase = (long)(mBase + row) * 256 + q8 * 32;
    float va[32];
    #pragma unroll
    for (int j = 0; j < 8; ++j) {
        float4 v = *(const float4*)(Ain + gbase + j * 4);
        va[j*4+0] = v.x; va[j*4+1] = v.y; va[j*4+2] = v.z; va[j*4+3] = v.w;
    }
    if (doLN) {
        float s1 = 0.f, s2 = 0.f;
        #pragma unroll
        for (int j = 0; j < 32; ++j) { s1 += va[j]; s2 += va[j] * va[j]; }
        s1 += __shfl_xor(s1, 1); s2 += __shfl_xor(s2, 1);
        s1 += __shfl_xor(s1, 2); s2 += __shfl_xor(s2, 2);
        s1 += __shfl_xor(s1, 4); s2 += __shfl_xor(s2, 4);
        const float mean = s1 * (1.f / 256.f);
        const float var  = s2 * (1.f / 256.f) - mean * mean;
        const float rstd = rsqrtf(var + 1e-5f);
        #pragma unroll
        for (int j = 0; j < 8; ++j) {
            float4 g4 = *(const float4*)(g + q8 * 32 + j * 4);
            float4 b4 = *(const float4*)(b + q8 * 32 + j * 4);
            va[j*4+0] = (va[j*4+0] - mean) * rstd * g4.x + b4.x;
            va[j*4+1] = (va[j*4+1] - mean) * rstd * g4.y + b4.y;
            va[j*4+2] = (va[j*4+2] - mean) * rstd * g4.z + b4.z;
            va[j*4+3] = (va[j*4+3] - mean) * rstd * g4.w + b4.w;
        }
    }
    if (xout) {
        #pragma unroll
        for (int j = 0; j < 8; ++j) {
            float4 v;
            v.x = va[j*4+0]; v.y = va[j*4+1]; v.z = va[j*4+2]; v.w = va[j*4+3];
            *(float4*)(xout + gbase + j * 4) = v;
        }
    }
    if (pos) {
        #pragma unroll
        for (int j = 0; j < 8; ++j) {
            float4 p = *(const float4*)(pos + gbase + j * 4);
            va[j*4+0] += p.x; va[j*4+1] += p.y; va[j*4+2] += p.z; va[j*4+3] += p.w;
        }
    }
    #pragma unroll
    for (int j8 = 0; j8 < 4; ++j8) {
        short tmp[8];
        #pragma unroll
        for (int e = 0; e < 8; ++e) tmp[e] = f2bf(va[j8 * 8 + e]);
        *(bf16x8*)&As[row][q8 * 32 + j8 * 8] = *(bf16x8*)tmp;
    }
}

// ============ 32-row GEMM core, A resident in LDS (K=256), B streamed BK=64 ============
// Register-prefetch rotation: next chunk's loads issue before current MFMA block.
template<int NF>
__device__ __forceinline__ void core32_Alds(
    const unsigned short* __restrict__ Bt, int nBase,
    const short (*As)[264], short (*Bs)[72], f32x4 (&acc)[NF])
{
    const int t = threadIdx.x;
    const int lane = t & 63, wave = t >> 6;
    const int wr = wave >> 1, wc = wave & 1;
    const int lr = lane & 15;

    #pragma unroll
    for (int j = 0; j < NF; ++j) acc[j] = (f32x4){0.f, 0.f, 0.f, 0.f};

    bf16x8 rb[NF];
    #pragma unroll
    for (int q = 0; q < NF; ++q) {
        int flat = q * 256 + t, row = flat >> 3, cg = (flat & 7) * 8;
        rb[q] = *(const bf16x8*)(Bt + (long)(nBase + row) * 256 + cg);
    }

    #pragma unroll
    for (int k0 = 0; k0 < 256; k0 += 64) {
        __syncthreads();
        #pragma unroll
        for (int q = 0; q < NF; ++q) {
            int flat = q * 256 + t, row = flat >> 3, cg = (flat & 7) * 8;
            *(bf16x8*)&Bs[row][cg] = rb[q];
        }
        __syncthreads();
        if (k0 < 192) {
            #pragma unroll
            for (int q = 0; q < NF; ++q) {
                int flat = q * 256 + t, row = flat >> 3, cg = (flat & 7) * 8;
                rb[q] = *(const bf16x8*)(Bt + (long)(nBase + row) * 256 + k0 + 64 + cg);
            }
        }
        #pragma unroll
        for (int kk = 0; kk < 2; ++kk) {
            const int lks = kk * 32 + (lane >> 4) * 8;
            bf16x8 af = *(const bf16x8*)&As[wr * 16 + lr][k0 + lks];
            #pragma unroll
            for (int fn = 0; fn < NF; ++fn) {
                bf16x8 bfr = *(bf16x8*)&Bs[wc * (NF * 16) + fn * 16 + lr][lks];
                acc[fn] = __builtin_amdgcn_mfma_f32_16x16x32_bf16(af, bfr, acc[fn], 0, 0, 0);
            }
        }
    }
}

// ============ 32-row GEMM core, A bf16 from global, B streamed, BK=64, prefetch-rotated ============
template<int NF>
__device__ __forceinline__ void core32_g(
    const unsigned short* __restrict__ A, const unsigned short* __restrict__ Bt,
    int K, int mBase, int nBase, short (*As)[72], short (*Bs)[72],
    f32x4 (&acc)[NF])
{
    const int t = threadIdx.x;
    const int lane = t & 63, wave = t >> 6;
    const int wr = wave >> 1, wc = wave & 1;
    const int lr = lane & 15;
    const int arow = t >> 3, acg = (t & 7) * 8;

    #pragma unroll
    for (int j = 0; j < NF; ++j) acc[j] = (f32x4){0.f, 0.f, 0.f, 0.f};

    bf16x8 ra, rb[NF];
    ra = *(const bf16x8*)(A + (long)(mBase + arow) * K + acg);
    #pragma unroll
    for (int q = 0; q < NF; ++q) {
        int flat = q * 256 + t, row = flat >> 3, cg = (flat & 7) * 8;
        rb[q] = *(const bf16x8*)(Bt + (long)(nBase + row) * K + cg);
    }

    for (int k0 = 0; k0 < K; k0 += 64) {
        __syncthreads();
        *(bf16x8*)&As[arow][acg] = ra;
        #pragma unroll
        for (int q = 0; q < NF; ++q) {
            int flat = q * 256 + t, row = flat >> 3, cg = (flat & 7) * 8;
            *(bf16x8*)&Bs[row][cg] = rb[q];
        }
        __syncthreads();
        if (k0 + 64 < K) {
            ra = *(const bf16x8*)(A + (long)(mBase + arow) * K + k0 + 64 + acg);
            #pragma unroll
            for (int q = 0; q < NF; ++q) {
                int flat = q * 256 + t, row = flat >> 3, cg = (flat & 7) * 8;
                rb[q] = *(const bf16x8*)(Bt + (long)(nBase + row) * K + k0 + 64 + cg);
            }
        }
        #pragma unroll
        for (int kk = 0; kk < 2; ++kk) {
            const int lks = kk * 32 + (lane >> 4) * 8;
            bf16x8 af = *(bf16x8*)&As[wr * 16 + lr][lks];
            #pragma unroll
            for (int fn = 0; fn < NF; ++fn) {
                bf16x8 bfr = *(bf16x8*)&Bs[wc * (NF * 16) + fn * 16 + lr][lks];
                acc[fn] = __builtin_amdgcn_mfma_f32_16x16x32_bf16(af, bfr, acc[fn], 0, 0, 0);
            }
        }
    }
}

// ---------------- fused LN2 + projections (grid 170 x 5); 32-row tiles, BK=64 ----------------
__global__ __launch_bounds__(256) void proj_ln(
    const float* __restrict__ Ain, const float* __restrict__ pos,
    const float* __restrict__ g, const float* __restrict__ b,
    const unsigned short* __restrict__ WvT, const float* __restrict__ bv,
    const unsigned short* __restrict__ WofT, const float* __restrict__ bof,
    const unsigned short* __restrict__ WatT, const float* __restrict__ bat,
    unsigned short* __restrict__ value_bf, unsigned short* __restrict__ offraw,
    unsigned short* __restrict__ logits, float* __restrict__ xcur, int doLN)
{
    __shared__ short As[32][264];
    __shared__ short Bs[128][72];
    const int ny = blockIdx.y, mBase = blockIdx.x * 32;
    const unsigned short* Bp; const float* bias; int nBase, kind;
    if (ny < 2)      { Bp = WvT;  bias = bv;  nBase = ny * 128;       kind = 0; }
    else if (ny < 4) { Bp = WofT; bias = bof; nBase = (ny - 2) * 128; kind = 1; }
    else             { Bp = WatT; bias = bat; nBase = 0;              kind = 2; }

    prep_A32(Ain, g, b, (kind > 0) ? pos : nullptr,
             (doLN && ny == 0) ? xcur : nullptr, mBase, doLN, As);

    f32x4 acc[4];
    core32_Alds<4>(Bp, nBase, As, Bs, acc);

    const int lane = threadIdx.x & 63, wave = threadIdx.x >> 6;
    const int wr = wave >> 1, wc = wave & 1;
    #pragma unroll
    for (int fn = 0; fn < 4; ++fn)
        #pragma unroll
        for (int r = 0; r < 4; ++r) {
            int m = mBase + wr * 16 + (lane >> 4) * 4 + r;
            int n = nBase + wc * 64 + fn * 16 + (lane & 15);
            float v = acc[fn][r] + bias[n];
            if (kind == 0)      value_bf[(long)m * 256 + n] = (unsigned short)f2bf(v);
            else if (kind == 1) offraw[(long)m * 256 + n] = (unsigned short)f2bf(v);
            else                logits[(long)m * 128 + n] = (unsigned short)f2bf(v);
        }
}

// ---------------- fused LN1 + W1 GEMM + relu (grid 170 x 4, NF=8, 32x256 tile) ----------------
__global__ __launch_bounds__(256) void gemm_w1ln(
    const float* __restrict__ Ain, const float* __restrict__ g,
    const float* __restrict__ b, const unsigned short* __restrict__ W1T,
    const float* __restrict__ bias, unsigned short* __restrict__ hbuf,
    float* __restrict__ xout)
{
    __shared__ short As[32][264];
    __shared__ short Bs[256][72];
    const int mBase = blockIdx.x * 32, nBase = blockIdx.y * 256;

    prep_A32(Ain, g, b, nullptr, (blockIdx.y == 0) ? xout : nullptr, mBase, 1, As);

    f32x4 acc[8];
    core32_Alds<8>(W1T, nBase, As, Bs, acc);

    const int lane = threadIdx.x & 63, wave = threadIdx.x >> 6;
    const int wr = wave >> 1, wc = wave & 1;
    #pragma unroll
    for (int fn = 0; fn < 8; ++fn)
        #pragma unroll
        for (int r = 0; r < 4; ++r) {
            int m = mBase + wr * 16 + (lane >> 4) * 4 + r;
            int n = nBase + wc * 128 + fn * 16 + (lane & 15);
            float v = fmaxf(acc[fn][r] + bias[n], 0.f);
            hbuf[(long)m * 1024 + n] = (unsigned short)f2bf(v);
        }
}

// ---------------- plain GEMM (N=256) + bias + residual -> fp32 (grid 170 x 4, 32x64 tile) ----------------
__global__ __launch_bounds__(256) void gemm_res(
    const unsigned short* __restrict__ A, const unsigned short* __restrict__ Bt,
    const float* __restrict__ bias, const float* __restrict__ res,
    float* __restrict__ out, int K)
{
    __shared__ short As[32][72];
    __shared__ short Bs[64][72];
    const int mBase = blockIdx.x * 32, nBase = blockIdx.y * 64;
    f32x4 acc[2];
    core32_g<2>(A, Bt, K, mBase, nBase, As, Bs, acc);

    const int lane = threadIdx.x & 63, wave = threadIdx.x >> 6;
    const int wr = wave >> 1, wc = wave & 1;
    #pragma unroll
    for (int fn = 0; fn < 2; ++fn)
        #pragma unroll
        for (int r = 0; r < 4; ++r) {
            int m = mBase + wr * 16 + (lane >> 4) * 4 + r;
            int n = nBase + wc * 32 + fn * 16 + (lane & 15);
            out[(long)m * 256 + n] = acc[fn][r] + bias[n] + res[(long)m * 256 + n];
        }
}

// ---------------- MSDA sampling v6: all 16 gathers hoisted before FMA ----------------
__global__ __launch_bounds__(256) void msda2(
    const unsigned short* __restrict__ value, const unsigned short* __restrict__ offraw,
    const unsigned short* __restrict__ logits, const float* __restrict__ vr,
    unsigned short* __restrict__ outB)
{
    const int t = threadIdx.x;
    const int q = t >> 7, tt = t & 127;
    const int s = blockIdx.x * 2 + q;

    __shared__ int4   sIdx[2][128];
    __shared__ float4 sW[2][128];

    {
        const int pt = tt & 15, l = pt >> 2;

        float lg = bf2f(logits[(long)s * 128 + tt]);
        float m = lg;
        #pragma unroll
        for (int o = 1; o < 16; o <<= 1) m = fmaxf(m, __shfl_xor(m, o));
        float e = expf(lg - m);
        float sum = e;
        #pragma unroll
        for (int o = 1; o < 16; o <<= 1) sum += __shfl_xor(sum, o);
        float aw = e / sum;

        int ls = (s < 4096) ? 0 : (s < 5120) ? 1 : (s < 5376) ? 2 : 3;
        int lw = c_logW[ls];
        int Wq = c_HW[ls];
        int rem = s - c_start[ls];
        int qi = rem >> lw, qj = rem & (Wq - 1);
        float xh = (qj + 0.5f) / (vr[ls * 2 + 1] * (float)Wq);
        float yh = (qi + 0.5f) / (vr[ls * 2 + 0] * (float)Wq);

        const int Wl = c_HW[l], sl = c_start[l];
        const float fW = (float)Wl;
        float refx = xh * vr[l * 2 + 1];
        float refy = yh * vr[l * 2 + 0];
        unsigned int uoxy = *(const unsigned int*)(offraw + (long)s * 256 + tt * 2);
        float ox = lo_f(uoxy), oy = hi_f(uoxy);
        float x = refx * fW + ox - 0.5f;
        float y = refy * fW + oy - 0.5f;
        float x0f = floorf(x), y0f = floorf(y);
        float fx = x - x0f, fy = y - y0f;
        int x0 = (int)x0f, y0 = (int)y0f;
        int x1 = x0 + 1, y1 = y0 + 1;
        float vx0 = (x0 >= 0 && x0 < Wl) ? 1.f : 0.f;
        float vx1 = (x1 >= 0 && x1 < Wl) ? 1.f : 0.f;
        float vy0 = (y0 >= 0 && y0 < Wl) ? 1.f : 0.f;
        float vy1 = (y1 >= 0 && y1 < Wl) ? 1.f : 0.f;
        int cx0 = min(max(x0, 0), Wl - 1), cx1 = min(max(x1, 0), Wl - 1);
        int cy0 = min(max(y0, 0), Wl - 1), cy1 = min(max(y1, 0), Wl - 1);

        int4 id4;
        id4.x = sl + cy0 * Wl + cx0;
        id4.y = sl + cy0 * Wl + cx1;
        id4.z = sl + cy1 * Wl + cx0;
        id4.w = sl + cy1 * Wl + cx1;
        sIdx[q][tt] = id4;
        float4 w4;
        w4.x = aw * (1.f - fx) * (1.f - fy) * vx0 * vy0;
        w4.y = aw * fx * (1.f - fy) * vx1 * vy0;
        w4.z = aw * (1.f - fx) * fy * vx0 * vy1;
        w4.w = aw * fx * fy * vx1 * vy1;
        sW[q][tt] = w4;
    }
    __syncthreads();

    // phase 2: h = tt>>4, pg = (tt>>2)&3, dq = tt&3 (dq fastest -> coalesced)
    const int h = tt >> 4, pg = (tt >> 2) & 3, dq = tt & 3;
    const int cb = h * 32 + dq * 8;

    int4   ids[4];
    float4 w4s[4];
    #pragma unroll
    for (int p = 0; p < 4; ++p) {
        const int ei = h * 16 + pg * 4 + p;
        ids[p] = sIdx[q][ei];
        w4s[p] = sW[q][ei];
    }
    u32x4 u[16];
    #pragma unroll
    for (int p = 0; p < 4; ++p) {
        u[p*4+0] = *(const u32x4*)(value + (long)ids[p].x * 256 + cb);
        u[p*4+1] = *(const u32x4*)(value + (long)ids[p].y * 256 + cb);
        u[p*4+2] = *(const u32x4*)(value + (long)ids[p].z * 256 + cb);
        u[p*4+3] = *(const u32x4*)(value + (long)ids[p].w * 256 + cb);
    }

    float a8[8] = {0.f,0.f,0.f,0.f,0.f,0.f,0.f,0.f};
    #pragma unroll
    for (int p = 0; p < 4; ++p) {
        float4 w = w4s[p];
        #pragma unroll
        for (int j = 0; j < 4; ++j) {
            a8[2*j]   += w.x * lo_f(u[p*4+0][j]) + w.y * lo_f(u[p*4+1][j])
                       + w.z * lo_f(u[p*4+2][j]) + w.w * lo_f(u[p*4+3][j]);
            a8[2*j+1] += w.x * hi_f(u[p*4+0][j]) + w.y * hi_f(u[p*4+1][j])
                       + w.z * hi_f(u[p*4+2][j]) + w.w * hi_f(u[p*4+3][j]);
        }
    }
    #pragma unroll
    for (int j = 0; j < 8; ++j) {
        a8[j] += __shfl_xor(a8[j], 4);
        a8[j] += __shfl_xor(a8[j], 8);
    }
    if (pg == 0) {
        short o8[8];
        #pragma unroll
        for (int j = 0; j < 8; ++j) o8[j] = f2bf(a8[j]);
        *(bf16x8*)(outB + (long)s * 256 + cb) = *(bf16x8*)o8;
    }
}

// ---------------- final LayerNorm: one wave per row ----------------
__global__ __launch_bounds__(256) void ln4f(
    const float* __restrict__ in, const float* __restrict__ g,
    const float* __restrict__ b, float* __restrict__ out)
{
    const int wave = threadIdx.x >> 6, lane = threadIdx.x & 63;
    const int s = blockIdx.x * 4 + wave;
    f32x4 v = *(const f32x4*)(in + (long)s * 256 + lane * 4);

    float sum = v[0] + v[1] + v[2] + v[3];
    #pragma unroll
    for (int o = 1; o < 64; o <<= 1) sum += __shfl_xor(sum, o);
    const float mean = sum * (1.f / 256.f);

    f32x4 d = v - mean;
    float sq = d[0]*d[0] + d[1]*d[1] + d[2]*d[2] + d[3]*d[3];
    #pragma unroll
    for (int o = 1; o < 64; o <<= 1) sq += __shfl_xor(sq, o);
    const float rstd = rsqrtf(sq * (1.f / 256.f) + 1e-5f);

    f32x4 gg = *(const f32x4*)(g + lane * 4);
    f32x4 bb = *(const f32x4*)(b + lane * 4);
    f32x4 o4 = d * rstd * gg + bb;
    *(f32x4*)(out + (long)s * 256 + lane * 4) = o4;
}

extern "C" void kernel_launch(void* const* d_in, const int* in_sizes, int n_in,
                              void* d_out, int out_size, void* d_ws, size_t ws_size,
                              hipStream_t stream) {
    const float* src   = (const float*)d_in[0];
    const float* pos   = (const float*)d_in[1];
    const float* vr    = (const float*)d_in[2];
    const float* Wv    = (const float*)d_in[5];
    const float* bv    = (const float*)d_in[6];
    const float* Woff  = (const float*)d_in[7];
    const float* boff  = (const float*)d_in[8];
    const float* Wattn = (const float*)d_in[9];
    const float* battn = (const float*)d_in[10];
    const float* Wout  = (const float*)d_in[11];
    const float* bout  = (const float*)d_in[12];
    const float* ln1g  = (const float*)d_in[13];
    const float* ln1b  = (const float*)d_in[14];
    const float* W1    = (const float*)d_in[15];
    const float* b1    = (const float*)d_in[16];
    const float* W2    = (const float*)d_in[17];
    const float* b2    = (const float*)d_in[18];
    const float* ln2g  = (const float*)d_in[19];
    const float* ln2b  = (const float*)d_in[20];

    const int S = S_TOT, C = C_DIM;
    const long SC = (long)S * C;

    // fp32 region
    float* ws     = (float*)d_ws;
    float* tmp2   = ws;                        // SC f32 (layer output, pre-LN2)
    float* xcur   = tmp2 + SC;                 // SC f32 (LN2 out = layer input x)
    float* xln1   = xcur + SC;                 // SC f32 (LN1 out, residual for W2)
    // bf16 region
    unsigned short* offraw_bf = (unsigned short*)(xln1 + SC);      // SC
    unsigned short* logits_bf = offraw_bf + SC;                    // S*128
    unsigned short* value_bf  = logits_bf + (long)S * 128;         // SC
    unsigned short* msda_bf   = value_bf + SC;                     // SC
    unsigned short* hbuf_bf   = msda_bf + SC;                      // S*F
    unsigned short* WT        = hbuf_bf + (long)S * F_DIM;         // 4521984

    const unsigned short* WvT  = WT + 0;
    const unsigned short* WofT = WT + 393216;
    const unsigned short* WatT = WT + 786432;
    const unsigned short* WouT = WT + 983040;
    const unsigned short* W1T  = WT + 1376256;
    const unsigned short* W2T  = WT + 2949120;

    prep_weights<<<1104, 256, 0, stream>>>(Wv, Woff, Wattn, Wout, W1, W2, WT);

    for (int i = 0; i < N_LAYERS; ++i) {
        const float* Ain = (i == 0) ? src : tmp2;
        const float* g2  = (i == 0) ? nullptr : ln2g + (long)(i - 1) * C;
        const float* bb2 = (i == 0) ? nullptr : ln2b + (long)(i - 1) * C;
        const float* resWout = (i == 0) ? src : xcur;

        proj_ln<<<dim3(170, 5), 256, 0, stream>>>(
            Ain, pos, g2, bb2,
            WvT + (long)i * 65536, bv + (long)i * C,
            WofT + (long)i * 65536, boff + (long)i * 256,
            WatT + (long)i * 32768, battn + (long)i * 128,
            value_bf, offraw_bf, logits_bf, xcur, (i == 0) ? 0 : 1);

        msda2<<<S / 2, 256, 0, stream>>>(value_bf, offraw_bf, logits_bf, vr, msda_bf);

        gemm_res<<<dim3(170, 4), 256, 0, stream>>>(
            msda_bf, WouT + (long)i * 65536, bout + (long)i * C, resWout, tmp2, 256);

        gemm_w1ln<<<dim3(170, 4), 256, 0, stream>>>(
            tmp2, ln1g + (long)i * C, ln1b + (long)i * C,
            W1T + (long)i * 262144, b1 + (long)i * F_DIM, hbuf_bf, xln1);

        gemm_res<<<dim3(170, 4), 256, 0, stream>>>(
            hbuf_bf, W2T + (long)i * 262144, b2 + (long)i * C, xln1, tmp2, 1024);
    }

    ln4f<<<S / 4, 256, 0, stream>>>(
        tmp2, ln2g + (long)(N_LAYERS - 1) * C, ln2b + (long)(N_LAYERS - 1) * C,
        (float*)d_out);
}